// Round 17
// baseline (333.208 us; speedup 1.0000x reference)
//
#include <hip/hip_runtime.h>
#include <math.h>

// FundusQuantumLayer — MEASUREMENT ROUND (split T-codegen vs T-structural).
// Real pipeline unchanged (R16, 20.7us). Added: two REP=16 diagnostic
// kernels writing to d_ws scratch, to appear in rocprof top-5 with counters:
//   fq_diag_f4: exact R16 body (f4 AS4 coefficient loads)
//   fq_diag_sc: same body, SCALAR float AS4 loads (4 named floats per coeff,
//               no vector construction -> no VGPR materialization possible)
// R12 baseline: R7 body REP=16 = 180us (~830 VALU/sample, 98.4% busy).
// Pre-committed: f4~175 & sc~100 => vector-load bloat -> real kernel goes
// scalar next. both~175 => bloat elsewhere. both~100 => structural floor.

typedef float f4 __attribute__((ext_vector_type(4)));
typedef const f4 __attribute__((address_space(4)))* c4ptr;
typedef const float __attribute__((address_space(4)))* cfptr;

__global__ void fq_setup(const float* __restrict__ w, float4* __restrict__ Ct) {
    __shared__ float2 sU[16][16];      // U[row][col] (re,im) of shared block
    __shared__ float  sReM[4][16][16]; // Re(U^dag Z_q U)
    const int tid = threadIdx.x;

    {   // ---- Stage A: thread (r,c) holds U[r][c].
        const int r = tid & 15, c = tid >> 4;
        float ar = (r == c) ? 1.f : 0.f, ai = 0.f;
#pragma unroll
        for (int l = 0; l < 3; ++l) {
#pragma unroll
            for (int q = 0; q < 4; ++q) {
                const int m = 1 << (3 - q);          // qubit 0 = MSB
                {   // RY
                    float th = w[(l*4 + q)*2 + 0];
                    float cg = __cosf(0.5f*th), sg = __sinf(0.5f*th);
                    float obr = __shfl_xor(ar, m, 64);
                    float obi = __shfl_xor(ai, m, 64);
                    float t2 = (r & m) ? sg : -sg;
                    ar = cg*ar + t2*obr;
                    ai = cg*ai + t2*obi;
                }
                {   // RZ
                    float ph = w[(l*4 + q)*2 + 1];
                    float cp = __cosf(0.5f*ph), sp = __sinf(0.5f*ph);
                    float t2 = (r & m) ? sp : -sp;
                    float nr = cp*ar - t2*ai;
                    float ni = cp*ai + t2*ar;
                    ar = nr; ai = ni;
                }
            }
#pragma unroll
            for (int e = 0; e < 4; ++e) {            // CNOT ring
                const int mc = 1 << (3 - e);
                const int mt = 1 << (3 - ((e + 1) & 3));
                float obr = __shfl_xor(ar, mt, 64);
                float obi = __shfl_xor(ai, mt, 64);
                if (r & mc) { ar = obr; ai = obi; }
            }
        }
        sU[r][c] = make_float2(ar, ai);
    }
    __syncthreads();

    {   // ---- Stage B: ReM[q][i][j] = sum_k z_q(k) Re(conj(U[k][i]) U[k][j])
        const int i = tid >> 4, j = tid & 15;
        float s0 = 0.f, s1 = 0.f, s2 = 0.f, s3 = 0.f;
#pragma unroll
        for (int k = 0; k < 16; ++k) {
            float2 uik = sU[k][i], ujk = sU[k][j];
            float pr = uik.x*ujk.x + uik.y*ujk.y;
            s0 += (k & 8) ? -pr : pr;
            s1 += (k & 4) ? -pr : pr;
            s2 += (k & 2) ? -pr : pr;
            s3 += (k & 1) ? -pr : pr;
        }
        sReM[0][i][j] = s0; sReM[1][i][j] = s1;
        sReM[2][i][j] = s2; sReM[3][i][j] = s3;
    }
    __syncthreads();

    // ---- Stage C: Ct[k81].q = tr(M_q P_{k81})/16, digits: 0=I 1=Z 2=X
    for (int idx = tid; idx < 324; idx += 256) {
        int q = idx / 81, k81 = idx % 81;
        int p0 = k81/27, p1 = (k81/9)%3, p2 = (k81/3)%3, p3 = k81%3;
        int xm = 0, zm = 0;
        if (p0 == 1) zm |= 8; else if (p0 == 2) xm |= 8;
        if (p1 == 1) zm |= 4; else if (p1 == 2) xm |= 4;
        if (p2 == 1) zm |= 2; else if (p2 == 2) xm |= 2;
        if (p3 == 1) zm |= 1; else if (p3 == 2) xm |= 1;
        float sum = 0.f;
#pragma unroll
        for (int j = 0; j < 16; ++j) {
            float sgn = (__popc(j & zm) & 1) ? -1.f : 1.f;
            sum += sgn * sReM[q][j ^ xm][j];
        }
        ((float*)Ct)[k81*4 + q] = sum * 0.0625f;
    }
}

// ---- 18 named g-products from 8 trig values (shared by all bodies) ----
#define GDEFS \
    const float g01_0 = 1.f; \
    const float g01_1 = c1,      g01_2 = s1; \
    const float g01_3 = c0,      g01_6 = s0; \
    const float g01_4 = c0 * c1, g01_5 = c0 * s1; \
    const float g01_7 = s0 * c1, g01_8 = s0 * s1; \
    const float g23_0 = 1.f; \
    const float g23_1 = c3,      g23_2 = s3; \
    const float g23_3 = c2,      g23_6 = s2; \
    const float g23_4 = c2 * c3, g23_5 = c2 * s3; \
    const float g23_7 = s2 * c3, g23_8 = s2 * s3;

// ---- f4-load a-group (R16 form) ----
#define TB4(a,b,G) { f4 c = C[(a)*9+(b)]; \
    t0=fmaf(c[0],(G),t0); t1=fmaf(c[1],(G),t1); \
    t2=fmaf(c[2],(G),t2); t3=fmaf(c[3],(G),t3); }
#define TA4(a, GA) { float t0=0.f,t1=0.f,t2=0.f,t3=0.f; \
    TB4(a,0,g23_0) TB4(a,1,g23_1) TB4(a,2,g23_2) \
    TB4(a,3,g23_3) TB4(a,4,g23_4) TB4(a,5,g23_5) \
    TB4(a,6,g23_6) TB4(a,7,g23_7) TB4(a,8,g23_8) \
    A0=fmaf(t0,(GA),A0); A1=fmaf(t1,(GA),A1); \
    A2=fmaf(t2,(GA),A2); A3=fmaf(t3,(GA),A3); }

// ---- scalar-load a-group (no vector construction anywhere) ----
#define TBS(a,b,G) { \
    float cc0 = Cf[((a)*9+(b))*4+0]; float cc1 = Cf[((a)*9+(b))*4+1]; \
    float cc2 = Cf[((a)*9+(b))*4+2]; float cc3 = Cf[((a)*9+(b))*4+3]; \
    t0=fmaf(cc0,(G),t0); t1=fmaf(cc1,(G),t1); \
    t2=fmaf(cc2,(G),t2); t3=fmaf(cc3,(G),t3); }
#define TAS(a, GA) { float t0=0.f,t1=0.f,t2=0.f,t3=0.f; \
    TBS(a,0,g23_0) TBS(a,1,g23_1) TBS(a,2,g23_2) \
    TBS(a,3,g23_3) TBS(a,4,g23_4) TBS(a,5,g23_5) \
    TBS(a,6,g23_6) TBS(a,7,g23_7) TBS(a,8,g23_8) \
    A0=fmaf(t0,(GA),A0); A1=fmaf(t1,(GA),A1); \
    A2=fmaf(t2,(GA),A2); A3=fmaf(t3,(GA),A3); }

// ---- real kernel (R16, unchanged) ----
__global__ __launch_bounds__(256) void fq_main(const float4* __restrict__ x,
                                               const float* __restrict__ Ct,
                                               float4* __restrict__ out) {
    const int i = blockIdx.x * 256 + threadIdx.x;
    c4ptr C = (c4ptr)(unsigned long long)Ct;

    float4 xv = x[i];
    float c0 = __cosf(xv.x), s0 = __sinf(xv.x);
    float c1 = __cosf(xv.y), s1 = __sinf(xv.y);
    float c2 = __cosf(xv.z), s2 = __sinf(xv.z);
    float c3 = __cosf(xv.w), s3 = __sinf(xv.w);
    GDEFS
    float A0 = 0.f, A1 = 0.f, A2 = 0.f, A3 = 0.f;
    TA4(0, g01_0) TA4(1, g01_1) TA4(2, g01_2)
    TA4(3, g01_3) TA4(4, g01_4) TA4(5, g01_5)
    TA4(6, g01_6) TA4(7, g01_7) TA4(8, g01_8)
    out[i] = make_float4(A0, A1, A2, A3);
}

// ---- diagnostic 1: R16 body, f4 loads, REP=16 ----
__global__ __launch_bounds__(256) void fq_diag_f4(const float4* __restrict__ x,
                                                  const float* __restrict__ Ct,
                                                  float4* __restrict__ dout) {
    const int i = blockIdx.x * 256 + threadIdx.x;
    float4 xv = x[i];
    float4 o = make_float4(0.f, 0.f, 0.f, 0.f);
#pragma unroll 1
    for (int k = 0; k < 16; ++k) {
        float xx = xv.x, xy = xv.y, xz = xv.z, xw = xv.w;
        asm volatile("" : "+v"(xx), "+v"(xy), "+v"(xz), "+v"(xw));
        unsigned long long Cp = (unsigned long long)Ct;
        asm volatile("" : "+s"(Cp));
        c4ptr C = (c4ptr)Cp;
        float c0 = __cosf(xx), s0 = __sinf(xx);
        float c1 = __cosf(xy), s1 = __sinf(xy);
        float c2 = __cosf(xz), s2 = __sinf(xz);
        float c3 = __cosf(xw), s3 = __sinf(xw);
        GDEFS
        float A0 = 0.f, A1 = 0.f, A2 = 0.f, A3 = 0.f;
        TA4(0, g01_0) TA4(1, g01_1) TA4(2, g01_2)
        TA4(3, g01_3) TA4(4, g01_4) TA4(5, g01_5)
        TA4(6, g01_6) TA4(7, g01_7) TA4(8, g01_8)
        o = make_float4(A0, A1, A2, A3);
        asm volatile("" : "+v"(o.x), "+v"(o.y), "+v"(o.z), "+v"(o.w));
    }
    dout[i] = o;
}

// ---- diagnostic 2: scalar s_load body, REP=16 ----
__global__ __launch_bounds__(256) void fq_diag_sc(const float4* __restrict__ x,
                                                  const float* __restrict__ Ct,
                                                  float4* __restrict__ dout) {
    const int i = blockIdx.x * 256 + threadIdx.x;
    float4 xv = x[i];
    float4 o = make_float4(0.f, 0.f, 0.f, 0.f);
#pragma unroll 1
    for (int k = 0; k < 16; ++k) {
        float xx = xv.x, xy = xv.y, xz = xv.z, xw = xv.w;
        asm volatile("" : "+v"(xx), "+v"(xy), "+v"(xz), "+v"(xw));
        unsigned long long Cp = (unsigned long long)Ct;
        asm volatile("" : "+s"(Cp));
        cfptr Cf = (cfptr)Cp;
        float c0 = __cosf(xx), s0 = __sinf(xx);
        float c1 = __cosf(xy), s1 = __sinf(xy);
        float c2 = __cosf(xz), s2 = __sinf(xz);
        float c3 = __cosf(xw), s3 = __sinf(xw);
        GDEFS
        float A0 = 0.f, A1 = 0.f, A2 = 0.f, A3 = 0.f;
        TAS(0, g01_0) TAS(1, g01_1) TAS(2, g01_2)
        TAS(3, g01_3) TAS(4, g01_4) TAS(5, g01_5)
        TAS(6, g01_6) TAS(7, g01_7) TAS(8, g01_8)
        o = make_float4(A0, A1, A2, A3);
        asm volatile("" : "+v"(o.x), "+v"(o.y), "+v"(o.z), "+v"(o.w));
    }
    dout[i] = o;
}

extern "C" void kernel_launch(void* const* d_in, const int* in_sizes, int n_in,
                              void* d_out, int out_size, void* d_ws, size_t ws_size,
                              hipStream_t stream) {
    const float* x = (const float*)d_in[0];     // [B,4] f32
    const float* w = (const float*)d_in[1];     // [3,4,2] f32
    float4* Ct = (float4*)d_ws;                 // 81 float4 table at d_ws[0]
    // diag scratch output well past the table (d_ws is 256MB per poison fills)
    float4* dscratch = (float4*)((char*)d_ws + (1 << 20));

    fq_setup<<<1, 256, 0, stream>>>(w, Ct);

    const int B = in_sizes[0] / 4;              // 1048576
    fq_main<<<B / 256, 256, 0, stream>>>((const float4*)x, (const float*)Ct,
                                         (float4*)d_out);
    // Diagnostics (write to workspace; timed but not validated):
    fq_diag_f4<<<B / 256, 256, 0, stream>>>((const float4*)x, (const float*)Ct,
                                            dscratch);
    fq_diag_sc<<<B / 256, 256, 0, stream>>>((const float4*)x, (const float*)Ct,
                                            dscratch);
}